// Round 7
// baseline (441.388 us; speedup 1.0000x reference)
//
#include <hip/hip_runtime.h>

typedef _Float16 f16;
typedef f16 f16x2 __attribute__((ext_vector_type(2)));
typedef f16 f16x8 __attribute__((ext_vector_type(8)));
typedef float f32x2 __attribute__((ext_vector_type(2)));
typedef float f32x4 __attribute__((ext_vector_type(4)));

#define T_STEPS 512
#define INPUT   12
#define HID     20
#define KDIM    32           // 12 + 20 == MFMA K exactly
#define BSTRIDE 40           // padded row stride (f16) -> conflict-free b128 reads
#define BATCH   16           // batches per block (MFMA N)
#define WPB     5            // 5 waves x 16 gate-rows = 80 = 4*H
#define BLOCK   (WPB * 64)

// raw barrier: drain LDS ops only (x prefetch stays in flight on vmcnt)
static __device__ __forceinline__ void block_barrier() {
    asm volatile("s_waitcnt lgkmcnt(0)\n\ts_barrier" ::: "memory");
}

__global__ __launch_bounds__(BLOCK) void lstm_kernel(
    const float* __restrict__ x,      // [8192,512,12]
    const float* __restrict__ w_ih,   // [80,12]
    const float* __restrict__ w_hh,   // [80,20]
    const float* __restrict__ b_ih,   // [80]
    const float* __restrict__ b_hh,   // [80]
    const float* __restrict__ w_out,  // [10,20]
    const float* __restrict__ b_out,  // [10]
    float* __restrict__ out)          // [8192,10]
{
    // Row-permuted combined weights, pre-scaled by -log2(e) (sigmoid gates) or
    // +2*log2(e) (g gate) so the activation chain needs no scaling muls.
    // Tile row m (of wave w) = gate (m&3) of unit 4w+(m>>2) -> lane (q,c)
    // acc regs 0..3 = i,f,g,o of unit 4w+q for batch c.
    __shared__ __align__(16) f16 Wc[80][KDIM];                 // 5 KB
    __shared__ __align__(16) f16 Bbuf[2][BATCH][BSTRIDE];      // 2.5 KB, [x(12)|h(20)|pad]

    const int tid  = threadIdx.x;
    const int wid  = tid >> 6;
    const int lane = tid & 63;
    const int c    = lane & 15;        // batch column (MFMA N, and A-row m)
    const int q    = lane >> 4;        // k-slice / D-row-quad

    // ---- build permuted, pre-scaled weight matrix (once) ----
    for (int i = tid; i < 80 * KDIM; i += BLOCK) {
        int n = i >> 5, k = i & 31;
        int g = n & 3;                       // gate (i,f,g,o)
        int u = 4 * (n >> 4) + ((n >> 2) & 3);
        int row = g * HID + u;               // original row of [w_ih | w_hh]
        float v = (k < INPUT) ? w_ih[row * INPUT + k] : w_hh[row * HID + (k - INPUT)];
        float sc = (g == 2) ? 2.8853900817779268f : -1.4426950408889634f;
        Wc[n][k] = (f16)(v * sc);
    }

    // ---- per-lane (batch, unit) ownership + scaled bias as MFMA C ----
    const int u = 4 * wid + q;         // unit 0..19
    f32x4 cbias;
#pragma unroll
    for (int r = 0; r < 4; ++r) {
        float sc = (r == 2) ? 2.8853900817779268f : -1.4426950408889634f;
        cbias[r] = sc * (b_ih[r * HID + u] + b_hh[r * HID + u]);
    }

    // zero h(-1) region of buf 0 (16 batches x 20 units via 320 lanes)
    Bbuf[0][c][INPUT + u] = (f16)0.f;

    // ---- x loaders: 96 lanes spread evenly (<=20 per wave), xi-pairs ----
    // loader L = wid*20 + lane (lane<20, L<96): batch xb=L/6, xi=2*(L%6)
    const int  L     = wid * 20 + lane;
    const bool xload = (lane < 20) && (L < 96);
    const int  xb    = L / 6;
    const int  xi    = 2 * (L - 6 * xb);
    const float* xptr = x + (size_t)(blockIdx.x * BATCH + xb) * (T_STEPS * INPUT) + xi;

    // 4-deep prefetch queue of xi-pairs: q[j] holds x(t+1+j), reloaded 4 ahead
    f32x2 z2 = {0.f, 0.f};
    f32x2 q0 = z2, q1 = z2, q2 = z2, q3 = z2;
    if (xload) {
        f32x2 x0 = *(const f32x2*)xptr;          // x(0) pair
        f16x2 xc; xc[0] = (f16)x0[0]; xc[1] = (f16)x0[1];
        *(f16x2*)&Bbuf[0][xb][xi] = xc;          // stage x(0)
        q0 = *(const f32x2*)(xptr + 1 * INPUT);
        q1 = *(const f32x2*)(xptr + 2 * INPUT);
        q2 = *(const f32x2*)(xptr + 3 * INPUT);
        q3 = *(const f32x2*)(xptr + 4 * INPUT);
    }
    __syncthreads();                             // Wc + x(0) + h(-1) visible

    // ---- constant A fragment: A[m=c][k=8q+j] from own wave's tile ----
    const f16x8 afragW = *(const f16x8*)&Wc[16 * wid + c][q * 8];

    float cc = 0.f;                              // scaled cell: 2*log2(e)*c

    // one recurrence step; pj = buffer parity (compile-time after inlining)
    auto step = [&](int pj, f32x2& qreg, int tload) {
        // B fragment: B[k=8q+j][n=c] (16B, conflict-free, issued at barrier exit)
        f16x8 bfrag = *(const f16x8*)&Bbuf[pj][c][q * 8];

        // stage x(t+1) into next buffer; reload queue slot with x(t+5)
        if (xload) {
            f16x2 xc; xc[0] = (f16)qreg[0]; xc[1] = (f16)qreg[1];
            *(f16x2*)&Bbuf[pj ^ 1][xb][xi] = xc;
            int tl = tload < T_STEPS ? tload : T_STEPS - 1;
            qreg = *(const f32x2*)(xptr + (size_t)tl * INPUT);
        }

        // gates (+scaled bias via C operand): regs 0..3 = i,f,g,o of (c, u)
        f32x4 acc = __builtin_amdgcn_mfma_f32_16x16x32_f16(afragW, bfrag, cbias, 0, 0, 0);

        // latency-optimal activations (scaled-cell form, parallel sigmoids):
        //   acc_i/f/o = -log2(e)*a  -> sig = rcp(1 + 2^acc)
        //   acc_g     = 2*log2(e)*a -> g2 = 2.885*tanh(a) = fma(-5.771, rg, 2.885)
        //   cc        = 2*log2(e)*c -> tanh(c) = 1 - 2*rcp(1 + 2^cc)
        float ei = __builtin_amdgcn_exp2f(acc[0]);
        float ef = __builtin_amdgcn_exp2f(acc[1]);
        float eg = __builtin_amdgcn_exp2f(acc[2]);
        float eo = __builtin_amdgcn_exp2f(acc[3]);
        float ig = __builtin_amdgcn_rcpf(1.f + ei);
        float fg = __builtin_amdgcn_rcpf(1.f + ef);
        float rg = __builtin_amdgcn_rcpf(1.f + eg);
        float og = __builtin_amdgcn_rcpf(1.f + eo);
        float g2 = __builtin_fmaf(-5.7707801635558536f, rg, 2.8853900817779268f);
        cc = __builtin_fmaf(fg, cc, ig * g2);
        float et = __builtin_amdgcn_exp2f(cc);
        float rt = __builtin_amdgcn_rcpf(1.f + et);
        float th = __builtin_fmaf(-2.f, rt, 1.f);
        float h  = og * th;

        Bbuf[pj ^ 1][c][INPUT + u] = (f16)h;     // publish h(t)
        block_barrier();                         // one barrier per step
    };

#pragma unroll 1
    for (int t4 = 0; t4 < T_STEPS; t4 += 4) {
        step(0, q0, t4 + 5);
        step(1, q1, t4 + 6);
        step(0, q2, t4 + 7);
        step(1, q3, t4 + 8);
    }

    // ---- output projection: T even -> h(T-1) sits in Bbuf[0] ----
    if (tid < BATCH * 10) {
        int ob = tid / 10, oo = tid % 10;
        float s = b_out[oo];
#pragma unroll
        for (int u2 = 0; u2 < HID; ++u2)
            s += w_out[oo * HID + u2] * (float)Bbuf[0][ob][INPUT + u2];
        out[(size_t)(blockIdx.x * BATCH + ob) * 10 + oo] = s;
    }
}

extern "C" void kernel_launch(void* const* d_in, const int* in_sizes, int n_in,
                              void* d_out, int out_size, void* d_ws, size_t ws_size,
                              hipStream_t stream) {
    const float* x     = (const float*)d_in[0];
    const float* w_ih  = (const float*)d_in[1];
    const float* w_hh  = (const float*)d_in[2];
    const float* b_ih  = (const float*)d_in[3];
    const float* b_hh  = (const float*)d_in[4];
    const float* w_out = (const float*)d_in[5];
    const float* b_out = (const float*)d_in[6];
    float* out = (float*)d_out;

    const int blocks = 8192 / BATCH;   // 512 blocks x 5 waves; 2 blocks/CU
    hipLaunchKernelGGL(lstm_kernel, dim3(blocks), dim3(BLOCK), 0, stream,
                       x, w_ih, w_hh, b_ih, b_hh, w_out, b_out, out);
}

// Round 8
// 427.547 us; speedup vs baseline: 1.0324x; 1.0324x over previous
//
#include <hip/hip_runtime.h>

typedef _Float16 f16;
typedef f16 f16x8 __attribute__((ext_vector_type(8)));
typedef float f32x4 __attribute__((ext_vector_type(4)));

#define T_STEPS 512
#define INPUT   12
#define HID     20
#define KDIM    32           // 12 + 20 == MFMA K exactly
#define BSTRIDE 40           // padded row stride (f16) -> conflict-free b128 reads
#define BATCH   16           // batches per block (MFMA N)
#define WPB     5            // 5 waves x 16 gate-rows = 80 = 4*H
#define BLOCK   (WPB * 64)

// raw barrier: drain LDS ops only (x prefetch stays in flight on vmcnt)
static __device__ __forceinline__ void block_barrier() {
    asm volatile("s_waitcnt lgkmcnt(0)\n\ts_barrier" ::: "memory");
}

__global__ __launch_bounds__(BLOCK) void lstm_kernel(
    const float* __restrict__ x,      // [8192,512,12]
    const float* __restrict__ w_ih,   // [80,12]
    const float* __restrict__ w_hh,   // [80,20]
    const float* __restrict__ b_ih,   // [80]
    const float* __restrict__ b_hh,   // [80]
    const float* __restrict__ w_out,  // [10,20]
    const float* __restrict__ b_out,  // [10]
    float* __restrict__ out)          // [8192,10]
{
    // Row-permuted combined weights, pre-scaled by -log2(e) (sigmoid gates) or
    // +2*log2(e) (g gate) so the activation chain needs no leading scale-muls.
    // Tile row m (of wave w) = gate (m&3) of unit 4w+(m>>2) -> lane (q,c)
    // acc regs 0..3 = i,f,g,o of unit 4w+q for batch c.
    __shared__ __align__(16) f16 Wc[80][KDIM];                 // 5 KB
    __shared__ __align__(16) f16 Bbuf[2][BATCH][BSTRIDE];      // 2.5 KB, [x(12)|h(20)|pad]

    const int tid  = threadIdx.x;
    const int wid  = tid >> 6;
    const int lane = tid & 63;
    const int col  = lane & 15;        // MFMA N index = batch
    const int quad = lane >> 4;

    // ---- build permuted, pre-scaled weight matrix (once) ----
    for (int i = tid; i < 80 * KDIM; i += BLOCK) {
        int n = i >> 5, k = i & 31;
        int g = n & 3;                       // gate (i,f,g,o)
        int u = 4 * (n >> 4) + ((n >> 2) & 3);
        int row = g * HID + u;               // original row of [w_ih | w_hh]
        float v = (k < INPUT) ? w_ih[row * INPUT + k] : w_hh[row * HID + (k - INPUT)];
        float sc = (g == 2) ? 2.8853900817779268f : -1.4426950408889634f;
        Wc[n][k] = (f16)(v * sc);
    }

    // ---- per-lane (batch, unit) ownership ----
    const int b = col;                 // batch 0..15
    const int u = 4 * wid + quad;      // unit 0..19

    // scaled combined bias as MFMA C operand: reg r = scaled bias of gate r
    f32x4 cbias;
#pragma unroll
    for (int g = 0; g < 4; ++g) {
        float sc = (g == 2) ? 2.8853900817779268f : -1.4426950408889634f;
        cbias[g] = sc * (b_ih[g * HID + u] + b_hh[g * HID + u]);
    }

    // zero h region of buf 0
    Bbuf[0][b][INPUT + u] = (f16)0.f;

    // ---- x loader (r0 layout): tids 0..191 (waves 0..2), one float/step ----
    const bool xload = tid < BATCH * INPUT;
    const int  xb    = tid / INPUT;
    const int  xi    = tid % INPUT;
    const float* xptr = x + (size_t)(blockIdx.x * BATCH + xb) * (T_STEPS * INPUT) + xi;

    // 4-deep prefetch queue: q[j] holds x(t+1) for body j, reloaded 4 ahead.
    float q0 = 0.f, q1 = 0.f, q2 = 0.f, q3 = 0.f;
    if (xload) {
        Bbuf[0][xb][xi] = (f16)xptr[0];          // stage x(0)
        q0 = xptr[1 * INPUT];                    // x(1)
        q1 = xptr[2 * INPUT];                    // x(2)
        q2 = xptr[3 * INPUT];                    // x(3)
        q3 = xptr[4 * INPUT];                    // x(4)
    }
    __syncthreads();                             // Wc + x(0) + h(-1) visible

    // ---- constant A fragment: A[m=lane&15][k=quad*8+j] from own wave's tile ----
    const f16x8 afragW = *(const f16x8*)&Wc[16 * wid + col][quad * 8];

    float cc = 0.f;                              // scaled cell: 2*log2(e)*c

    // one recurrence step; pj = buffer parity (compile-time after inlining)
    auto step = [&](int pj, float& qreg, int tload) {
        // B fragment: B[k=quad*8+j][n=col] (16B, conflict-free)
        f16x8 bfrag = *(const f16x8*)&Bbuf[pj][col][quad * 8];

        // stage x(t+1) into next buffer; reload queue slot with x(t+5)
        if (xload) Bbuf[pj ^ 1][xb][xi] = (f16)qreg;
        int tl = tload > T_STEPS - 1 ? T_STEPS - 1 : tload;
        if (xload) qreg = xptr[(size_t)tl * INPUT];

        // gates (+scaled bias via C operand): regs 0..3 = i,f,g,o of (b, u)
        f32x4 acc = __builtin_amdgcn_mfma_f32_16x16x32_f16(afragW, bfrag, cbias, 0, 0, 0);

        // latency-optimal activations (scaled-cell form, parallel sigmoids):
        //   acc_i/f/o = -log2(e)*a  -> sig  = rcp(1 + 2^acc)
        //   acc_g     = 2*log2(e)*a -> g2   = 2.885*tanh(a) = fma(-5.771, rg, 2.885)
        //   cc        = 2*log2(e)*c -> tanh = 1 - 2*rcp(1 + 2^cc)
        float ei = __builtin_amdgcn_exp2f(acc[0]);
        float ef = __builtin_amdgcn_exp2f(acc[1]);
        float eg = __builtin_amdgcn_exp2f(acc[2]);
        float eo = __builtin_amdgcn_exp2f(acc[3]);
        float ig = __builtin_amdgcn_rcpf(1.f + ei);
        float fg = __builtin_amdgcn_rcpf(1.f + ef);
        float rg = __builtin_amdgcn_rcpf(1.f + eg);
        float og = __builtin_amdgcn_rcpf(1.f + eo);
        float g2 = __builtin_fmaf(-5.7707801635558536f, rg, 2.8853900817779268f);
        cc = __builtin_fmaf(fg, cc, ig * g2);
        float et = __builtin_amdgcn_exp2f(cc);
        float rt = __builtin_amdgcn_rcpf(1.f + et);
        float th = __builtin_fmaf(-2.f, rt, 1.f);
        float h  = og * th;

        Bbuf[pj ^ 1][b][INPUT + u] = (f16)h;     // publish h(t)
        block_barrier();                         // one barrier per step
    };

#pragma unroll 1
    for (int t4 = 0; t4 < T_STEPS; t4 += 4) {
        step(0, q0, t4 + 5);
        step(1, q1, t4 + 6);
        step(0, q2, t4 + 7);
        step(1, q3, t4 + 8);
    }

    // ---- output projection: T even -> h(T-1) sits in Bbuf[0] ----
    if (tid < BATCH * 10) {
        int ob = tid / 10, oo = tid % 10;
        float s = b_out[oo];
#pragma unroll
        for (int u2 = 0; u2 < HID; ++u2)
            s += w_out[oo * HID + u2] * (float)Bbuf[0][ob][INPUT + u2];
        out[(size_t)(blockIdx.x * BATCH + ob) * 10 + oo] = s;
    }
}

extern "C" void kernel_launch(void* const* d_in, const int* in_sizes, int n_in,
                              void* d_out, int out_size, void* d_ws, size_t ws_size,
                              hipStream_t stream) {
    const float* x     = (const float*)d_in[0];
    const float* w_ih  = (const float*)d_in[1];
    const float* w_hh  = (const float*)d_in[2];
    const float* b_ih  = (const float*)d_in[3];
    const float* b_hh  = (const float*)d_in[4];
    const float* w_out = (const float*)d_in[5];
    const float* b_out = (const float*)d_in[6];
    float* out = (float*)d_out;

    const int blocks = 8192 / BATCH;   // 512 blocks x 5 waves; 2 blocks/CU
    hipLaunchKernelGGL(lstm_kernel, dim3(blocks), dim3(BLOCK), 0, stream,
                       x, w_ih, w_hh, b_ih, b_hh, w_out, b_out, out);
}